// Round 8
// baseline (242.291 us; speedup 1.0000x reference)
//
#include <hip/hip_runtime.h>

#define Bn 128
#define Qn 32
#define Dn 512
#define En 300
#define Kn 21
#define NC 16                  // 32-doc chunks per batch
#define CH 32
#define NKT 10                 // k-tiles of 32 (covers 320 >= 300, zero-padded)
#define LDE 40                 // shorts per row within one k-tile (80 B)
#define TILE_SH (CH * LDE)     // 1280 shorts per k-tile
#define SIMLD 36               // sim row stride (floats)
#define NTHR 256
#define QK (Qn * Kn)           // 672 partials per (b,c)
#define POFF ((size_t)Bn * NC * QK * 4)   // counter offset in ws bytes

typedef __attribute__((ext_vector_type(8))) short bf16x8;
typedef __attribute__((ext_vector_type(4))) float f32x4;

// LDS map (bytes):
//   dbuf [0, 25600)       short[NKT][CH][LDE]
//   qbuf [25600, 51200)   same; dead after af-hoist -> sim float[32][SIMLD] aliases it
//   idx  [51200, 51456)   int[64]: 32 doc tokens, 32 q tokens
//   flag [51456, 51460)
//   reduce scratch aliases smem base (float[672+21]) after everything is dead
#define SMEM_BYTES 51464       // -> 3 blocks/CU

__device__ __forceinline__ float dot4(float4 a, float4 b) {
    return a.x * b.x + a.y * b.y + a.z * b.z + a.w * b.w;
}

#define ISSUE(arr, tok)                                                        \
    _Pragma("unroll")                                                          \
    for (int j2 = 0; j2 < NKT; ++j2) {                                         \
        const int k = j2 * 32 + il * 4;                                        \
        float4 v = {0.f, 0.f, 0.f, 0.f};                                       \
        if (k <= 296 && (tok) >= 0)                                            \
            v = *(const float4*)(table + (size_t)(tok) * En + k);              \
        arr[j2] = v;                                                           \
    }

#define COMMIT(arr, dst)                                                       \
    {                                                                          \
        float ss = 0.f;                                                        \
        _Pragma("unroll")                                                      \
        for (int j2 = 0; j2 < NKT; ++j2) ss += dot4(arr[j2], arr[j2]);         \
        ss += __shfl_xor(ss, 1);                                               \
        ss += __shfl_xor(ss, 2);                                               \
        ss += __shfl_xor(ss, 4);                                               \
        const float inv = 1.0f / fmaxf(sqrtf(ss), 1e-12f);                     \
        _Pragma("unroll")                                                      \
        for (int j2 = 0; j2 < NKT; ++j2) {                                     \
            const unsigned ax = __float_as_uint(arr[j2].x * inv) + 0x8000u;    \
            const unsigned ay = __float_as_uint(arr[j2].y * inv) + 0x8000u;    \
            const unsigned az = __float_as_uint(arr[j2].z * inv) + 0x8000u;    \
            const unsigned aw = __float_as_uint(arr[j2].w * inv) + 0x8000u;    \
            uint2 p;                                                           \
            p.x = __builtin_amdgcn_perm(ay, ax, 0x07060302u);                  \
            p.y = __builtin_amdgcn_perm(aw, az, 0x07060302u);                  \
            *(uint2*)&(dst)[j2 * TILE_SH + row * LDE + il * 4] = p;            \
        }                                                                      \
    }

__global__ __launch_bounds__(NTHR, 3)
void knrm_fused(const int* __restrict__ qidx, const int* __restrict__ didx,
                const int* __restrict__ qlen_arr, const int* __restrict__ dlen_arr,
                const float* __restrict__ table, const float* __restrict__ dense_w,
                const float* __restrict__ dense_b, float* __restrict__ partial,
                int* __restrict__ counters, float* __restrict__ out)
{
    // XCD-contiguous remap (2048 % 8 == 0, bijective): a batch's 16 blocks share an XCD
    const int g = blockIdx.x;
    const int idx2 = (g & 7) * 256 + (g >> 3);
    const int b = idx2 >> 4;
    const int c = idx2 & 15;
    const int dlen = dlen_arr[b];
    const int t = threadIdx.x;

    __shared__ __align__(16) char smem[SMEM_BYTES];
    short* dbuf = (short*)smem;
    short* qbuf = (short*)(smem + 25600);
    float* sim  = (float*)(smem + 25600);     // alias: live only after af-hoist sync
    int*   idxb = (int*)(smem + 51200);       // [64]
    int*   flag = (int*)(smem + 51456);

    const bool active = (c * CH < dlen);
    if (active) {
        // ---- stage tokens (-1 sentinel -> zero rows)
        if (t < CH) {
            const int doc = c * CH + t;
            idxb[t] = (doc < dlen) ? didx[b * Dn + doc] : -1;
        } else if (t < CH + Qn) {
            idxb[t] = qidx[b * Qn + (t - CH)];
        }
        __syncthreads();

        const int row = t >> 3;      // 32 rows, one per 8-lane octet
        const int il  = t & 7;

        // ---- issue q and d gathers together (one latency window), commit both
        float4 lq[NKT], ldd[NKT];
        const int qtok = idxb[CH + row];
        const int dtok = idxb[row];
        ISSUE(lq, qtok)
        ISSUE(ldd, dtok)
        COMMIT(lq, qbuf)
        COMMIT(ldd, dbuf)
        __syncthreads();             // qbuf+dbuf ready

        const int lane = t & 63;
        const int w = t >> 6;
        const int qt = w >> 1;
        const int dt = w & 1;
        const int frow = lane & 15;
        const int koct = lane >> 4;

        bf16x8 af[NKT];
        #pragma unroll
        for (int kt = 0; kt < NKT; ++kt)
            af[kt] = *(const bf16x8*)&qbuf[kt * TILE_SH + (qt * 16 + frow) * LDE + koct * 8];
        __syncthreads();             // all waves hoisted; qbuf dead -> sim alias live

        f32x4 accS = {0.f, 0.f, 0.f, 0.f};
        #pragma unroll
        for (int kt = 0; kt < NKT; ++kt) {
            bf16x8 bf = *(const bf16x8*)&dbuf[kt * TILE_SH + (dt * 16 + frow) * LDE + koct * 8];
            accS = __builtin_amdgcn_mfma_f32_16x16x32_bf16(af[kt], bf, accS, 0, 0, 0);
        }
        // C layout: col=frow (doc), row=koct*4+r (q within tile)
        #pragma unroll
        for (int r = 0; r < 4; ++r)
            sim[(qt * 16 + koct * 4 + r) * SIMLD + dt * 16 + frow] = accS[r];
        __syncthreads();

        // ---- pooling: thread = (q row, k-triple); stream 32 docs from sim
        const int pq = t >> 3;
        const int kg = t & 7;
        if (kg < 7) {
            float mu[3], cf[3];
            #pragma unroll
            for (int kk = 0; kk < 3; ++kk) {
                const int k = kg * 3 + kk;
                mu[kk] = (k == 0) ? 1.0f : 1.05f - 0.1f * (float)k;
                cf[kk] = (k == 0) ? -500000.0f : -50.0f;   // -1/(2*sigma^2)
            }
            float acc[3] = {0.f, 0.f, 0.f};
            const int cbase = c * CH;
            #pragma unroll
            for (int f4 = 0; f4 < 8; ++f4) {
                const float4 sv = *(const float4*)&sim[pq * SIMLD + f4 * 4];
                #pragma unroll
                for (int e = 0; e < 4; ++e) {
                    const float se = (e == 0) ? sv.x : (e == 1) ? sv.y : (e == 2) ? sv.z : sv.w;
                    const float s = (cbase + f4 * 4 + e < dlen) ? se : 1.0e3f;  // masked -> exp 0
                    #pragma unroll
                    for (int kk = 0; kk < 3; ++kk) {
                        const float d = s - mu[kk];
                        acc[kk] += __expf(cf[kk] * d * d);
                    }
                }
            }
            float* pb = partial + (size_t)(b * NC + c) * QK + pq * Kn + kg * 3;
            pb[0] = acc[0]; pb[1] = acc[1]; pb[2] = acc[2];
        }
    }

    // ---- arrival: release fence + per-batch counter; 16th arriver finalizes
    __threadfence();                 // agent-scope release of partial stores
    __syncthreads();                 // all threads' stores precede the atomic
    if (t == 0) *flag = atomicAdd(&counters[b], 1);
    __syncthreads();
    if (*flag != NC - 1) return;

    // ---- finalize batch b (exactly one block per batch gets here)
    __threadfence();                 // acquire: invalidate stale cache lines
    const int qlen = qlen_arr[b];
    const int ncu = min((dlen + CH - 1) >> 5, NC);
    float* sq = (float*)smem;        // 672 + 21 floats; everything else dead
    float* lk = sq + QK;
    __syncthreads();
    for (int i = t; i < QK; i += NTHR) {
        const int q = i / Kn;
        float s = 0.f;
        for (int cc = 0; cc < ncu; ++cc)
            s += partial[(size_t)(b * NC + cc) * QK + i];
        sq[i] = (q < qlen) ? 0.01f * logf(fmaxf(s, 1e-10f)) : 0.f;
    }
    __syncthreads();
    if (t < Kn) {
        float l = 0.f;
        #pragma unroll
        for (int q = 0; q < Qn; ++q) l += sq[q * Kn + t];
        out[Bn + (size_t)b * Kn + t] = l;   // log_pooling_sum (B,K)
        lk[t] = l;
    }
    __syncthreads();
    if (t == 0) {
        float sc = dense_b[0];
        #pragma unroll
        for (int k = 0; k < Kn; ++k) sc += lk[k] * dense_w[k];
        out[b] = sc;                        // score (B,)
    }
}

extern "C" void kernel_launch(void* const* d_in, const int* in_sizes, int n_in,
                              void* d_out, int out_size, void* d_ws, size_t ws_size,
                              hipStream_t stream)
{
    const int*   qidx  = (const int*)d_in[0];
    const int*   didx  = (const int*)d_in[1];
    const int*   qlen  = (const int*)d_in[2];
    const int*   dlen  = (const int*)d_in[3];
    const float* table = (const float*)d_in[4];
    const float* dw    = (const float*)d_in[5];
    const float* db    = (const float*)d_in[6];
    float* out     = (float*)d_out;
    float* partial = (float*)d_ws;                    // 5.5 MB, only active slices read
    int*   counters = (int*)((char*)d_ws + POFF);     // 128 ints, zeroed every launch

    hipMemsetAsync(counters, 0, Bn * sizeof(int), stream);
    knrm_fused<<<dim3(Bn * NC), dim3(NTHR), 0, stream>>>(
        qidx, didx, qlen, dlen, table, dw, db, partial, counters, out);
}

// Round 9
// 27.753 us; speedup vs baseline: 8.7303x; 8.7303x over previous
//
#include <hip/hip_runtime.h>

#define Bn 128
#define Qn 32
#define Dn 512
#define En 300
#define Kn 21
#define NC 16                  // 32-doc chunks per batch
#define CH 32
#define NKT 10                 // k-tiles of 32 (covers 320 >= 300, zero-padded)
#define LDE 40                 // shorts per row within one k-tile (80 B)
#define TILE_SH (CH * LDE)     // 1280 shorts per k-tile
#define SIMLD 36               // sim row stride (floats)
#define NTHR 256
#define QK (Qn * Kn)           // 672 partials per (b,c)

typedef __attribute__((ext_vector_type(8))) short bf16x8;
typedef __attribute__((ext_vector_type(4))) float f32x4;

// LDS map (bytes):
//   dbuf [0, 25600)       short[NKT][CH][LDE]
//   qbuf [25600, 51200)   same; dead after af-hoist -> sim float[32][SIMLD] aliases it
//   idx  [51200, 51456)   int[64]: 32 doc tokens, 32 q tokens
#define SMEM_BYTES 51456       // -> 3 blocks/CU

__device__ __forceinline__ float dot4(float4 a, float4 b) {
    return a.x * b.x + a.y * b.y + a.z * b.z + a.w * b.w;
}

#define ISSUE(arr, tok)                                                        \
    _Pragma("unroll")                                                          \
    for (int j2 = 0; j2 < NKT; ++j2) {                                         \
        const int k = j2 * 32 + il * 4;                                        \
        float4 v = {0.f, 0.f, 0.f, 0.f};                                       \
        if (k <= 296 && (tok) >= 0)                                            \
            v = *(const float4*)(table + (size_t)(tok) * En + k);              \
        arr[j2] = v;                                                           \
    }

#define COMMIT(arr, dst)                                                       \
    {                                                                          \
        float ss = 0.f;                                                        \
        _Pragma("unroll")                                                      \
        for (int j2 = 0; j2 < NKT; ++j2) ss += dot4(arr[j2], arr[j2]);         \
        ss += __shfl_xor(ss, 1);                                               \
        ss += __shfl_xor(ss, 2);                                               \
        ss += __shfl_xor(ss, 4);                                               \
        const float inv = 1.0f / fmaxf(sqrtf(ss), 1e-12f);                     \
        _Pragma("unroll")                                                      \
        for (int j2 = 0; j2 < NKT; ++j2) {                                     \
            const unsigned ax = __float_as_uint(arr[j2].x * inv) + 0x8000u;    \
            const unsigned ay = __float_as_uint(arr[j2].y * inv) + 0x8000u;    \
            const unsigned az = __float_as_uint(arr[j2].z * inv) + 0x8000u;    \
            const unsigned aw = __float_as_uint(arr[j2].w * inv) + 0x8000u;    \
            uint2 p;                                                           \
            p.x = __builtin_amdgcn_perm(ay, ax, 0x07060302u);                  \
            p.y = __builtin_amdgcn_perm(aw, az, 0x07060302u);                  \
            *(uint2*)&(dst)[j2 * TILE_SH + row * LDE + il * 4] = p;            \
        }                                                                      \
    }

__global__ __launch_bounds__(NTHR, 3)
void knrm_main(const int* __restrict__ qidx, const int* __restrict__ didx,
               const int* __restrict__ dlen_arr, const float* __restrict__ table,
               float* __restrict__ partial)
{
    // XCD-contiguous remap (2048 % 8 == 0, bijective): a batch's 16 blocks share an XCD
    const int g = blockIdx.x;
    const int idx2 = (g & 7) * 256 + (g >> 3);
    const int b = idx2 >> 4;
    const int c = idx2 & 15;
    const int dlen = dlen_arr[b];
    if (c * CH >= dlen) return;      // inactive: reduce kernel never reads this slice

    const int t = threadIdx.x;

    __shared__ __align__(16) char smem[SMEM_BYTES];
    short* dbuf = (short*)smem;
    short* qbuf = (short*)(smem + 25600);
    float* sim  = (float*)(smem + 25600);     // alias: live only after af-hoist sync
    int*   idxb = (int*)(smem + 51200);       // [64]

    // ---- stage tokens (-1 sentinel -> zero rows)
    if (t < CH) {
        const int doc = c * CH + t;
        idxb[t] = (doc < dlen) ? didx[b * Dn + doc] : -1;
    } else if (t < CH + Qn) {
        idxb[t] = qidx[b * Qn + (t - CH)];
    }
    __syncthreads();

    const int row = t >> 3;      // 32 rows, one per 8-lane octet
    const int il  = t & 7;

    // ---- issue q and d gathers together (one latency window), commit both
    float4 lq[NKT], ldd[NKT];
    const int qtok = idxb[CH + row];
    const int dtok = idxb[row];
    ISSUE(lq, qtok)
    ISSUE(ldd, dtok)
    COMMIT(lq, qbuf)
    COMMIT(ldd, dbuf)
    __syncthreads();             // qbuf+dbuf ready

    const int lane = t & 63;
    const int w = t >> 6;
    const int qt = w >> 1;
    const int dt = w & 1;
    const int frow = lane & 15;
    const int koct = lane >> 4;

    bf16x8 af[NKT];
    #pragma unroll
    for (int kt = 0; kt < NKT; ++kt)
        af[kt] = *(const bf16x8*)&qbuf[kt * TILE_SH + (qt * 16 + frow) * LDE + koct * 8];
    __syncthreads();             // all waves hoisted; qbuf dead -> sim alias live

    f32x4 accS = {0.f, 0.f, 0.f, 0.f};
    #pragma unroll
    for (int kt = 0; kt < NKT; ++kt) {
        bf16x8 bf = *(const bf16x8*)&dbuf[kt * TILE_SH + (dt * 16 + frow) * LDE + koct * 8];
        accS = __builtin_amdgcn_mfma_f32_16x16x32_bf16(af[kt], bf, accS, 0, 0, 0);
    }
    // C layout: col=frow (doc), row=koct*4+r (q within tile)
    #pragma unroll
    for (int r = 0; r < 4; ++r)
        sim[(qt * 16 + koct * 4 + r) * SIMLD + dt * 16 + frow] = accS[r];
    __syncthreads();

    // ---- pooling: thread = (q row, k-triple); stream 32 docs from sim
    const int pq = t >> 3;
    const int kg = t & 7;
    if (kg < 7) {
        float mu[3], cf[3];
        #pragma unroll
        for (int kk = 0; kk < 3; ++kk) {
            const int k = kg * 3 + kk;
            mu[kk] = (k == 0) ? 1.0f : 1.05f - 0.1f * (float)k;
            cf[kk] = (k == 0) ? -500000.0f : -50.0f;   // -1/(2*sigma^2)
        }
        float acc[3] = {0.f, 0.f, 0.f};
        const int cbase = c * CH;
        #pragma unroll
        for (int f4 = 0; f4 < 8; ++f4) {
            const float4 sv = *(const float4*)&sim[pq * SIMLD + f4 * 4];
            #pragma unroll
            for (int e = 0; e < 4; ++e) {
                const float se = (e == 0) ? sv.x : (e == 1) ? sv.y : (e == 2) ? sv.z : sv.w;
                const float s = (cbase + f4 * 4 + e < dlen) ? se : 1.0e3f;  // masked -> exp 0
                #pragma unroll
                for (int kk = 0; kk < 3; ++kk) {
                    const float d = s - mu[kk];
                    acc[kk] += __expf(cf[kk] * d * d);
                }
            }
        }
        float* pb = partial + (size_t)(b * NC + c) * QK + pq * Kn + kg * 3;
        pb[0] = acc[0]; pb[1] = acc[1]; pb[2] = acc[2];
    }
}

__global__ __launch_bounds__(704)
void knrm_reduce(const int* __restrict__ qlen_arr, const int* __restrict__ dlen_arr,
                 const float* __restrict__ partial, const float* __restrict__ dense_w,
                 const float* __restrict__ dense_b, float* __restrict__ out)
{
    __shared__ float sq[QK];
    __shared__ float lk[Kn];
    const int b = blockIdx.x;
    const int t = threadIdx.x;
    const int qlen = qlen_arr[b];
    const int ncu = min((dlen_arr[b] + CH - 1) >> 5, NC);   // only written slices
    if (t < QK) {
        const int q = t / Kn;
        float s = 0.f;
        for (int c = 0; c < ncu; ++c)
            s += partial[(size_t)(b * NC + c) * QK + t];
        sq[t] = (q < qlen) ? 0.01f * logf(fmaxf(s, 1e-10f)) : 0.f;
    }
    __syncthreads();
    if (t < Kn) {
        float l = 0.f;
        #pragma unroll
        for (int q = 0; q < Qn; ++q) l += sq[q * Kn + t];
        out[Bn + (size_t)b * Kn + t] = l;   // log_pooling_sum (B,K)
        lk[t] = l;
    }
    __syncthreads();
    if (t == 0) {
        float sc = dense_b[0];
        #pragma unroll
        for (int k = 0; k < Kn; ++k) sc += lk[k] * dense_w[k];
        out[b] = sc;                        // score (B,)
    }
}

extern "C" void kernel_launch(void* const* d_in, const int* in_sizes, int n_in,
                              void* d_out, int out_size, void* d_ws, size_t ws_size,
                              hipStream_t stream)
{
    const int*   qidx  = (const int*)d_in[0];
    const int*   didx  = (const int*)d_in[1];
    const int*   qlen  = (const int*)d_in[2];
    const int*   dlen  = (const int*)d_in[3];
    const float* table = (const float*)d_in[4];
    const float* dw    = (const float*)d_in[5];
    const float* db    = (const float*)d_in[6];
    float* out     = (float*)d_out;
    float* partial = (float*)d_ws;   // 5.5 MB; only slices with c < ceil(dlen/32) are read

    knrm_main<<<dim3(Bn * NC), dim3(NTHR), 0, stream>>>(qidx, didx, dlen, table, partial);
    knrm_reduce<<<dim3(Bn), dim3(704), 0, stream>>>(qlen, dlen, partial, dw, db, out);
}